// Round 1
// baseline (320.385 us; speedup 1.0000x reference)
//
#include <hip/hip_runtime.h>

// GCNConv forward: out = D^{-1/2} (A + I) D^{-1/2} (x @ W) + b
// N = 1,000,000 nodes (< 2^20), E = 4,000,000 edges, F = 16.
//
// Pipeline (tiles = 1024 consecutive dst nodes, 977 tiles):
//   K0 init:  cursor[b] = b*CAP (line-padded cursors)
//   K1 bin:   per 8192-edge block: edges staged in REGISTERS (single global
//             pass), LDS hist -> wave-shfl scan (1 barrier, was 18) -> one
//             global atomic per (block,tile) -> in-LDS counting sort ->
//             coalesced run writes of packed (cl<<20|src).
//   K2 csr:   per tile: edges staged in registers (no pk[] LDS -> 33.8 KB
//             LDS -> 4 blocks/CU, was 2), hist -> wave-shfl scan -> pd
//             (ptr,deg packed int2), re-sort srcs by local dst, write back
//             in place; fused node transform hs = (x@W)*dinv in bf16.
//   K3 gather: thread per (node,feature). Flat 2-deep dependency: all <=8
//             adj words loaded unconditionally (values masked; dead slots
//             gather hs row 0 which stays L1-hot), then <=8 independent hs
//             gathers. dinv recomputed from deg (no dinv array). out via
//             nontemporal stores so 64 MB of streaming writes don't evict
//             hs from L2. Rare tail loop for deg>8 (~2% of nodes).

#define F 16
#define TILE 1024
#define CAP 5120          // mean 4094/tile, sd ~64 -> +16 sd headroom
#define CHUNK 8192
#define CUR_STRIDE 16     // 1 cursor per 64B line

static __device__ __forceinline__ unsigned short f2bf(float f) {
    unsigned u = __float_as_uint(f);
    unsigned r = (u + 0x7FFFu + ((u >> 16) & 1u)) >> 16;
    return (unsigned short)r;
}
static __device__ __forceinline__ float bf2f(unsigned short u) {
    return __uint_as_float(((unsigned)u) << 16);
}

// Exclusive scan of one value per thread across a 512-thread block.
// Wave-level shfl scan + 8-wave combine: 1 barrier (replaces 18-barrier
// Hillis-Steele). wsum must be >=8 ints of LDS.
static __device__ __forceinline__ int excl_scan_512(int s, int t, int* wsum) {
    int lane = t & 63, wv = t >> 6;
    int incl = s;
    #pragma unroll
    for (int off = 1; off < 64; off <<= 1) {
        int y = __shfl_up(incl, off, 64);
        if (lane >= off) incl += y;
    }
    if (lane == 63) wsum[wv] = incl;
    __syncthreads();
    int woff = 0;
    #pragma unroll
    for (int w = 0; w < 8; w++) {
        int v = wsum[w];
        if (w < wv) woff += v;
    }
    return woff + incl - s;
}

__global__ void init_kernel(int* __restrict__ cursor, int nbuck) {
    int b = blockIdx.x * blockDim.x + threadIdx.x;
    if (b < nbuck) cursor[b * CUR_STRIDE] = b * CAP;
}

__global__ void __launch_bounds__(512)
bin_kernel(const int* __restrict__ row, const int* __restrict__ col,
           int* __restrict__ cursor, unsigned* __restrict__ adj, int E, int nbuck) {
    __shared__ int hist[TILE];
    __shared__ int lstart[TILE];
    __shared__ int cnt2[TILE];
    __shared__ int slotBase[TILE];
    __shared__ int wsum[8];
    __shared__ unsigned sortedE[CHUNK];        // 32 KB
    __shared__ unsigned short sortedBk[CHUNK]; // 16 KB

    int t = threadIdx.x;
    for (int i = t; i < TILE; i += 512) { hist[i] = 0; cnt2[i] = 0; }
    __syncthreads();

    int base = blockIdx.x * CHUNK;
    int nE = E - base; if (nE > CHUNK) nE = CHUNK;

    // stage edges in registers: single global pass over (row,col)
    int c[16], r[16];
    #pragma unroll
    for (int q = 0; q < 16; q++) {
        int i = t + q * 512;
        if (i < nE) {
            c[q] = col[base + i];
            r[q] = row[base + i];
        } else { c[q] = -1; r[q] = 0; }
    }
    #pragma unroll
    for (int q = 0; q < 16; q++)
        if (c[q] >= 0) atomicAdd(&hist[c[q] >> 10], 1);
    __syncthreads();

    int a0 = hist[2 * t], a1 = hist[2 * t + 1];
    int s = a0 + a1;
    int excl = excl_scan_512(s, t, wsum);
    lstart[2 * t]     = excl;
    lstart[2 * t + 1] = excl + a0;
    if (a0 > 0 && 2 * t < nbuck)
        slotBase[2 * t] = atomicAdd(&cursor[(2 * t) * CUR_STRIDE], a0);
    if (a1 > 0 && 2 * t + 1 < nbuck)
        slotBase[2 * t + 1] = atomicAdd(&cursor[(2 * t + 1) * CUR_STRIDE], a1);
    __syncthreads();

    #pragma unroll
    for (int q = 0; q < 16; q++) {
        if (c[q] >= 0) {
            int bk = c[q] >> 10;
            int li = lstart[bk] + atomicAdd(&cnt2[bk], 1);
            sortedE[li]  = (((unsigned)(c[q] & (TILE - 1))) << 20) | (unsigned)r[q];
            sortedBk[li] = (unsigned short)bk;
        }
    }
    __syncthreads();

    for (int i = t; i < nE; i += 512) {
        int bk = sortedBk[i];
        int g = slotBase[bk] + (i - lstart[bk]);
        if (g < (bk + 1) * CAP) adj[g] = sortedE[i];
    }
}

// Per tile: build per-node CSR (sort region by local dst, in place), write
// packed (ptr,deg), then fused node transform hs = (x@W)*dinv (bf16).
__global__ void __launch_bounds__(512)
csr_node_kernel(const int* __restrict__ cursor, unsigned* __restrict__ adj,
                const float* __restrict__ x, const float* __restrict__ W,
                int2* __restrict__ pd, unsigned short* __restrict__ hs, int N) {
    __shared__ unsigned srt[CAP];      // 20 KB sorted srcs
    __shared__ int hist[TILE];
    __shared__ int lstart[TILE];
    __shared__ int cnt2[TILE];
    __shared__ int wsum[8];
    __shared__ float sW[256];
    // total ~33.8 KB -> 4 blocks/CU (was 55 KB -> 2 blocks/CU)

    int t = threadIdx.x, b = blockIdx.x;
    if (t < 256) sW[t] = W[t];
    for (int i = t; i < TILE; i += 512) { hist[i] = 0; cnt2[i] = 0; }
    __syncthreads();

    int base = b * CAP;
    int cnt_total = cursor[b * CUR_STRIDE] - base;
    if (cnt_total > CAP) cnt_total = CAP;

    // stage region in registers (CAP/512 = 10 per thread)
    unsigned e[10];
    #pragma unroll
    for (int q = 0; q < 10; q++) {
        int i = t + q * 512;
        if (i < cnt_total) {
            unsigned ee = adj[base + i];
            e[q] = ee;
            atomicAdd(&hist[ee >> 20], 1);
        } else e[q] = 0xFFFFFFFFu;   // packed values are <= 0x3FFFFFFF
    }
    __syncthreads();

    int a0 = hist[2 * t], a1 = hist[2 * t + 1];
    int s = a0 + a1;
    int excl = excl_scan_512(s, t, wsum);
    lstart[2 * t]     = excl;
    lstart[2 * t + 1] = excl + a0;
    {
        int n0 = b * TILE + 2 * t, n1 = n0 + 1;
        if (n0 < N) pd[n0] = make_int2(base + excl,      a0);
        if (n1 < N) pd[n1] = make_int2(base + excl + a0, a1);
    }
    __syncthreads();

    // counting-sort srcs by local dst
    #pragma unroll
    for (int q = 0; q < 10; q++) {
        if (e[q] != 0xFFFFFFFFu) {
            int cl = e[q] >> 20;
            int pos = lstart[cl] + atomicAdd(&cnt2[cl], 1);
            srt[pos] = e[q] & 0xFFFFFu;
        }
    }
    __syncthreads();
    #pragma unroll
    for (int q = 0; q < 10; q++) {
        int i = t + q * 512;
        if (i < cnt_total) adj[base + i] = srt[i];   // in-place per-node CSR
    }

    // fused node transform (independent of the sort writes)
    #pragma unroll
    for (int p = 0; p < 2; p++) {
        int local = p * 512 + t;
        int node = b * TILE + local;
        if (node >= N) continue;
        float di = rsqrtf((float)hist[local] + 1.0f);

        const float4* xr = (const float4*)(x + (size_t)node * F);
        float4 x0 = xr[0], x1 = xr[1], x2 = xr[2], x3 = xr[3];
        float xv[16] = {x0.x, x0.y, x0.z, x0.w, x1.x, x1.y, x1.z, x1.w,
                        x2.x, x2.y, x2.z, x2.w, x3.x, x3.y, x3.z, x3.w};
        float hv[16];
        #pragma unroll
        for (int j = 0; j < 16; j++) hv[j] = 0.f;
        #pragma unroll
        for (int k = 0; k < 16; k++) {
            float xk = xv[k];
            const float4* wr = (const float4*)(sW + k * 16);
            float4 w0 = wr[0], w1 = wr[1], w2 = wr[2], w3 = wr[3];
            hv[0]  += xk * w0.x; hv[1]  += xk * w0.y; hv[2]  += xk * w0.z; hv[3]  += xk * w0.w;
            hv[4]  += xk * w1.x; hv[5]  += xk * w1.y; hv[6]  += xk * w1.z; hv[7]  += xk * w1.w;
            hv[8]  += xk * w2.x; hv[9]  += xk * w2.y; hv[10] += xk * w2.z; hv[11] += xk * w2.w;
            hv[12] += xk * w3.x; hv[13] += xk * w3.y; hv[14] += xk * w3.z; hv[15] += xk * w3.w;
        }
        unsigned pkk[8];
        #pragma unroll
        for (int q = 0; q < 8; q++)
            pkk[q] = (unsigned)f2bf(hv[2*q] * di) | ((unsigned)f2bf(hv[2*q+1] * di) << 16);
        uint4* hp = (uint4*)(hs + (size_t)node * F);
        hp[0] = make_uint4(pkk[0], pkk[1], pkk[2], pkk[3]);
        hp[1] = make_uint4(pkk[4], pkk[5], pkk[6], pkk[7]);
    }
}

__global__ void __launch_bounds__(256)
gather_kernel(const int2* __restrict__ pd, const unsigned* __restrict__ adj,
              const unsigned short* __restrict__ hs, const float* __restrict__ bias,
              float* __restrict__ out, int N) {
    int tid = blockIdx.x * blockDim.x + threadIdx.x;
    int g = tid >> 4;
    int j = tid & 15;
    if (g >= N) return;

    int2 p = pd[g];
    int p0 = p.x, d = p.y;

    float s0 = bf2f(hs[(size_t)g * F + j]);   // self-loop term
    float s1 = 0.f, s2 = 0.f, s3 = 0.f;

    // first (up to) 8 neighbors: unconditional adj loads (values masked;
    // over-read of <=28B past adj lands in the pd region of the same ws
    // allocation), then 8 independent hs gathers. Dead slots gather hs row 0
    // -> one L1-resident line, no exec-mask churn.
    unsigned r8[8];
    #pragma unroll
    for (int i = 0; i < 8; i++) {
        unsigned u = __builtin_nontemporal_load(adj + p0 + i);
        r8[i] = (i < d) ? u : 0u;
    }
    float v8[8];
    #pragma unroll
    for (int i = 0; i < 8; i++)
        v8[i] = (i < d) ? bf2f(hs[(size_t)r8[i] * F + j]) : 0.f;
    s0 += v8[0] + v8[4];
    s1 += v8[1] + v8[5];
    s2 += v8[2] + v8[6];
    s3 += v8[3] + v8[7];

    if (d > 8) {                              // ~2% of nodes (Poisson(4))
        for (int k = 8; k < d; k += 4) {
            unsigned rr[4];
            #pragma unroll
            for (int i = 0; i < 4; i++) {
                bool ok = (k + i) < d;
                unsigned u = __builtin_nontemporal_load(adj + p0 + k + (ok ? i : 0));
                rr[i] = ok ? u : 0u;
            }
            #pragma unroll
            for (int i = 0; i < 4; i++) {
                float vv = ((k + i) < d) ? bf2f(hs[(size_t)rr[i] * F + j]) : 0.f;
                if (i == 0) s0 += vv;
                else if (i == 1) s1 += vv;
                else if (i == 2) s2 += vv;
                else s3 += vv;
            }
        }
    }

    float di = rsqrtf((float)d + 1.0f);       // deg>=0, matches csr's dinv
    __builtin_nontemporal_store(di * (s0 + s1 + s2 + s3) + bias[j],
                                out + (size_t)g * F + j);
}

extern "C" void kernel_launch(void* const* d_in, const int* in_sizes, int n_in,
                              void* d_out, int out_size, void* d_ws, size_t ws_size,
                              hipStream_t stream) {
    const float* x  = (const float*)d_in[0];
    const int*   ei = (const int*)d_in[1];
    const float* W  = (const float*)d_in[2];
    const float* b  = (const float*)d_in[3];

    int N = in_sizes[0] / F;       // 1,000,000 (< 2^20, required for packing)
    int E = in_sizes[1] / 2;       // 4,000,000
    const int* row = ei;           // src
    const int* col = ei + E;       // dst

    float* out = (float*)d_out;
    int nbuck = (N + TILE - 1) / TILE;   // 977

    auto align_up = [](size_t v) { return (v + 255) & ~(size_t)255; };
    char* ws = (char*)d_ws;
    size_t off = 0;
    int* cursor = (int*)(ws + off);          off = align_up(off + (size_t)nbuck * CUR_STRIDE * 4);
    unsigned* adj = (unsigned*)(ws + off);   off = align_up(off + (size_t)nbuck * CAP * 4);
    int2* pd = (int2*)(ws + off);            off = align_up(off + (size_t)N * 8);
    unsigned short* hs = (unsigned short*)(ws + off); off = align_up(off + (size_t)N * F * 2);
    // ~60 MB total; pd MUST follow adj (gather over-reads <=28B past adj)

    init_kernel<<<(nbuck + 255) / 256, 256, 0, stream>>>(cursor, nbuck);
    bin_kernel <<<(E + CHUNK - 1) / CHUNK, 512, 0, stream>>>(row, col, cursor, adj, E, nbuck);
    csr_node_kernel<<<nbuck, 512, 0, stream>>>(cursor, adj, x, W, pd, hs, N);

    long long gthreads = (long long)N * F;
    gather_kernel<<<(int)((gthreads + 255) / 256), 256, 0, stream>>>
        (pd, adj, hs, b, out, N);
}

// Round 2
// 305.617 us; speedup vs baseline: 1.0483x; 1.0483x over previous
//
#include <hip/hip_runtime.h>

// GCNConv forward: out = D^{-1/2} (A + I) D^{-1/2} (x @ W) + b
// N = 1,000,000 nodes (< 2^20), E = 4,000,000 edges, F = 16.
//
// Pipeline (tiles = 1024 consecutive dst nodes, 977 tiles):
//   K0 init:  cursor[b] = b*CAP (line-padded cursors)
//   K1 bin:   per 8192-edge block: edges staged in REGISTERS, LDS hist ->
//             wave-shfl scan (1 barrier) -> one global atomic per
//             (block,tile) -> in-LDS counting sort (hist reused as running
//             cursor) -> coalesced run writes. Bucket id in the write phase
//             recovered by 10-step binary search over lstart (drops the
//             16 KB sortedBk array: LDS 68->44 KB, 2->3 blocks/CU).
//   K2 csr:   per tile: edges staged in registers, hist -> wave-shfl scan ->
//             pd (ptr,deg packed int2), re-sort srcs by local dst, write
//             back in place; fused node transform hs = (x@W)*dinv in bf16.
//   K3 gather: thread per (node,feature), round-0 structure restored (it
//             measured 126.8 us; the flat-8 + nontemporal variant regressed
//             to 143): plain loads, 2 independent dependent-chains, early
//             exit at deg, plain coalesced out store. Only deltas kept:
//             pd int2 (1 load for ptr+deg) and dinv recomputed from deg.

#define F 16
#define TILE 1024
#define CAP 5120          // mean 4094/tile, sd ~64 -> +16 sd headroom
#define CHUNK 8192
#define CUR_STRIDE 16     // 1 cursor per 64B line

static __device__ __forceinline__ unsigned short f2bf(float f) {
    unsigned u = __float_as_uint(f);
    unsigned r = (u + 0x7FFFu + ((u >> 16) & 1u)) >> 16;
    return (unsigned short)r;
}
static __device__ __forceinline__ float bf2f(unsigned short u) {
    return __uint_as_float(((unsigned)u) << 16);
}

// Exclusive scan of one value per thread across a 512-thread block.
// Wave-level shfl scan + 8-wave combine: 1 barrier. wsum: >=8 ints LDS.
static __device__ __forceinline__ int excl_scan_512(int s, int t, int* wsum) {
    int lane = t & 63, wv = t >> 6;
    int incl = s;
    #pragma unroll
    for (int off = 1; off < 64; off <<= 1) {
        int y = __shfl_up(incl, off, 64);
        if (lane >= off) incl += y;
    }
    if (lane == 63) wsum[wv] = incl;
    __syncthreads();
    int woff = 0;
    #pragma unroll
    for (int w = 0; w < 8; w++) {
        int v = wsum[w];
        if (w < wv) woff += v;
    }
    return woff + incl - s;
}

__global__ void init_kernel(int* __restrict__ cursor, int nbuck) {
    int b = blockIdx.x * blockDim.x + threadIdx.x;
    if (b < nbuck) cursor[b * CUR_STRIDE] = b * CAP;
}

__global__ void __launch_bounds__(512)
bin_kernel(const int* __restrict__ row, const int* __restrict__ col,
           int* __restrict__ cursor, unsigned* __restrict__ adj, int E, int nbuck) {
    __shared__ int hist[TILE];        // counts, then running sort cursor
    __shared__ int lstart[TILE];      // exclusive prefix (kept for write phase)
    __shared__ int slotBase[TILE];
    __shared__ int wsum[8];
    __shared__ unsigned sortedE[CHUNK];   // 32 KB
    // total ~44 KB -> 3 blocks/CU (was 68 KB -> 2)

    int t = threadIdx.x;
    for (int i = t; i < TILE; i += 512) hist[i] = 0;
    __syncthreads();

    int base = blockIdx.x * CHUNK;
    int nE = E - base; if (nE > CHUNK) nE = CHUNK;

    // stage edges in registers: single global pass over (row,col)
    int c[16], r[16];
    #pragma unroll
    for (int q = 0; q < 16; q++) {
        int i = t + q * 512;
        if (i < nE) {
            c[q] = col[base + i];
            r[q] = row[base + i];
        } else { c[q] = -1; r[q] = 0; }
    }
    #pragma unroll
    for (int q = 0; q < 16; q++)
        if (c[q] >= 0) atomicAdd(&hist[c[q] >> 10], 1);
    __syncthreads();

    int a0 = hist[2 * t], a1 = hist[2 * t + 1];
    int s = a0 + a1;
    int excl = excl_scan_512(s, t, wsum);   // one barrier inside
    lstart[2 * t]     = excl;
    lstart[2 * t + 1] = excl + a0;
    // reuse hist as the running placement cursor (absolute local index)
    hist[2 * t]     = excl;
    hist[2 * t + 1] = excl + a0;
    if (a0 > 0 && 2 * t < nbuck)
        slotBase[2 * t] = atomicAdd(&cursor[(2 * t) * CUR_STRIDE], a0);
    if (a1 > 0 && 2 * t + 1 < nbuck)
        slotBase[2 * t + 1] = atomicAdd(&cursor[(2 * t + 1) * CUR_STRIDE], a1);
    __syncthreads();

    #pragma unroll
    for (int q = 0; q < 16; q++) {
        if (c[q] >= 0) {
            int bk = c[q] >> 10;
            int li = atomicAdd(&hist[bk], 1);          // absolute position
            sortedE[li] = (((unsigned)(c[q] & (TILE - 1))) << 20) | (unsigned)r[q];
        }
    }
    __syncthreads();

    // write phase: recover bucket of position i by binary search over lstart
    // (upper_bound - 1; empty buckets have zero width so the result is the
    // unique non-empty bucket containing i). lstart[0] == 0 <= i always.
    for (int i = t; i < nE; i += 512) {
        int lo = 0, hi = TILE;
        #pragma unroll
        for (int it = 0; it < 10; it++) {
            int mid = (lo + hi) >> 1;
            if (lstart[mid] <= i) lo = mid; else hi = mid;
        }
        int bk = lo;
        int g = slotBase[bk] + (i - lstart[bk]);
        if (g < (bk + 1) * CAP) adj[g] = sortedE[i];
    }
}

// Per tile: build per-node CSR (sort region by local dst, in place), write
// packed (ptr,deg), then fused node transform hs = (x@W)*dinv (bf16).
__global__ void __launch_bounds__(512)
csr_node_kernel(const int* __restrict__ cursor, unsigned* __restrict__ adj,
                const float* __restrict__ x, const float* __restrict__ W,
                int2* __restrict__ pd, unsigned short* __restrict__ hs, int N) {
    __shared__ unsigned srt[CAP];      // 20 KB sorted srcs
    __shared__ int hist[TILE];
    __shared__ int lstart[TILE];
    __shared__ int cnt2[TILE];
    __shared__ int wsum[8];
    __shared__ float sW[256];
    // total ~33.8 KB -> 4 blocks/CU

    int t = threadIdx.x, b = blockIdx.x;
    if (t < 256) sW[t] = W[t];
    for (int i = t; i < TILE; i += 512) { hist[i] = 0; cnt2[i] = 0; }
    __syncthreads();

    int base = b * CAP;
    int cnt_total = cursor[b * CUR_STRIDE] - base;
    if (cnt_total > CAP) cnt_total = CAP;

    // stage region in registers (CAP/512 = 10 per thread)
    unsigned e[10];
    #pragma unroll
    for (int q = 0; q < 10; q++) {
        int i = t + q * 512;
        if (i < cnt_total) {
            unsigned ee = adj[base + i];
            e[q] = ee;
            atomicAdd(&hist[ee >> 20], 1);
        } else e[q] = 0xFFFFFFFFu;   // packed values are <= 0x3FFFFFFF
    }
    __syncthreads();

    int a0 = hist[2 * t], a1 = hist[2 * t + 1];
    int s = a0 + a1;
    int excl = excl_scan_512(s, t, wsum);
    lstart[2 * t]     = excl;
    lstart[2 * t + 1] = excl + a0;
    {
        int n0 = b * TILE + 2 * t, n1 = n0 + 1;
        if (n0 < N) pd[n0] = make_int2(base + excl,      a0);
        if (n1 < N) pd[n1] = make_int2(base + excl + a0, a1);
    }
    __syncthreads();

    // counting-sort srcs by local dst
    #pragma unroll
    for (int q = 0; q < 10; q++) {
        if (e[q] != 0xFFFFFFFFu) {
            int cl = e[q] >> 20;
            int pos = lstart[cl] + atomicAdd(&cnt2[cl], 1);
            srt[pos] = e[q] & 0xFFFFFu;
        }
    }
    __syncthreads();
    #pragma unroll
    for (int q = 0; q < 10; q++) {
        int i = t + q * 512;
        if (i < cnt_total) adj[base + i] = srt[i];   // in-place per-node CSR
    }

    // fused node transform (independent of the sort writes)
    #pragma unroll
    for (int p = 0; p < 2; p++) {
        int local = p * 512 + t;
        int node = b * TILE + local;
        if (node >= N) continue;
        float di = rsqrtf((float)hist[local] + 1.0f);

        const float4* xr = (const float4*)(x + (size_t)node * F);
        float4 x0 = xr[0], x1 = xr[1], x2 = xr[2], x3 = xr[3];
        float xv[16] = {x0.x, x0.y, x0.z, x0.w, x1.x, x1.y, x1.z, x1.w,
                        x2.x, x2.y, x2.z, x2.w, x3.x, x3.y, x3.z, x3.w};
        float hv[16];
        #pragma unroll
        for (int j = 0; j < 16; j++) hv[j] = 0.f;
        #pragma unroll
        for (int k = 0; k < 16; k++) {
            float xk = xv[k];
            const float4* wr = (const float4*)(sW + k * 16);
            float4 w0 = wr[0], w1 = wr[1], w2 = wr[2], w3 = wr[3];
            hv[0]  += xk * w0.x; hv[1]  += xk * w0.y; hv[2]  += xk * w0.z; hv[3]  += xk * w0.w;
            hv[4]  += xk * w1.x; hv[5]  += xk * w1.y; hv[6]  += xk * w1.z; hv[7]  += xk * w1.w;
            hv[8]  += xk * w2.x; hv[9]  += xk * w2.y; hv[10] += xk * w2.z; hv[11] += xk * w2.w;
            hv[12] += xk * w3.x; hv[13] += xk * w3.y; hv[14] += xk * w3.z; hv[15] += xk * w3.w;
        }
        unsigned pkk[8];
        #pragma unroll
        for (int q = 0; q < 8; q++)
            pkk[q] = (unsigned)f2bf(hv[2*q] * di) | ((unsigned)f2bf(hv[2*q+1] * di) << 16);
        uint4* hp = (uint4*)(hs + (size_t)node * F);
        hp[0] = make_uint4(pkk[0], pkk[1], pkk[2], pkk[3]);
        hp[1] = make_uint4(pkk[4], pkk[5], pkk[6], pkk[7]);
    }
}

__global__ void __launch_bounds__(256)
gather_kernel(const int2* __restrict__ pd, const unsigned* __restrict__ adj,
              const unsigned short* __restrict__ hs, const float* __restrict__ bias,
              float* __restrict__ out, int N) {
    int tid = blockIdx.x * blockDim.x + threadIdx.x;
    int g = tid >> 4;
    int j = tid & 15;
    if (g >= N) return;

    int2 p = pd[g];
    int p0 = p.x, d = p.y;
    int end = p0 + d;

    float a0 = bf2f(hs[(size_t)g * F + j]);   // self-loop term
    float a1 = 0.f;
    int k = p0;
    for (; k + 1 < end; k += 2) {             // 2 independent chains
        unsigned r0 = adj[k];
        unsigned r1 = adj[k + 1];
        a0 += bf2f(hs[(size_t)r0 * F + j]);
        a1 += bf2f(hs[(size_t)r1 * F + j]);
    }
    if (k < end) a1 += bf2f(hs[(size_t)adj[k] * F + j]);

    float di = rsqrtf((float)d + 1.0f);
    out[(size_t)g * F + j] = di * (a0 + a1) + bias[j];
}

extern "C" void kernel_launch(void* const* d_in, const int* in_sizes, int n_in,
                              void* d_out, int out_size, void* d_ws, size_t ws_size,
                              hipStream_t stream) {
    const float* x  = (const float*)d_in[0];
    const int*   ei = (const int*)d_in[1];
    const float* W  = (const float*)d_in[2];
    const float* b  = (const float*)d_in[3];

    int N = in_sizes[0] / F;       // 1,000,000 (< 2^20, required for packing)
    int E = in_sizes[1] / 2;       // 4,000,000
    const int* row = ei;           // src
    const int* col = ei + E;       // dst

    float* out = (float*)d_out;
    int nbuck = (N + TILE - 1) / TILE;   // 977

    auto align_up = [](size_t v) { return (v + 255) & ~(size_t)255; };
    char* ws = (char*)d_ws;
    size_t off = 0;
    int* cursor = (int*)(ws + off);          off = align_up(off + (size_t)nbuck * CUR_STRIDE * 4);
    unsigned* adj = (unsigned*)(ws + off);   off = align_up(off + (size_t)nbuck * CAP * 4);
    int2* pd = (int2*)(ws + off);            off = align_up(off + (size_t)N * 8);
    unsigned short* hs = (unsigned short*)(ws + off); off = align_up(off + (size_t)N * F * 2);
    // ~60 MB total

    init_kernel<<<(nbuck + 255) / 256, 256, 0, stream>>>(cursor, nbuck);
    bin_kernel <<<(E + CHUNK - 1) / CHUNK, 512, 0, stream>>>(row, col, cursor, adj, E, nbuck);
    csr_node_kernel<<<nbuck, 512, 0, stream>>>(cursor, adj, x, W, pd, hs, N);

    long long gthreads = (long long)N * F;
    gather_kernel<<<(int)((gthreads + 255) / 256), 256, 0, stream>>>
        (pd, adj, hs, b, out, N);
}